// Round 5
// baseline (222.404 us; speedup 1.0000x reference)
//
#include <hip/hip_runtime.h>

#define BN 8
#define NN 4096
#define DD 256   // D_FULL
#define MM 256   // num features
#define DV 256   // value dim
#define CHUNK 256
#define NC (NN / CHUNK)   // 16 chunks per batch

using f32x4 = __attribute__((ext_vector_type(4))) float;
using s16x8 = __attribute__((ext_vector_type(8))) short;

#define MFMA16(a, b, c) __builtin_amdgcn_mfma_f32_16x16x32_bf16(a, b, c, 0, 0, 0)

// ---------------------------------------------------------------------------
// Fragment-order layouts (per (b,c) chunk, 65536 elements each):
//  PhiQF[(jt*8 + ms)*4 + t][lane][e]  = phiQ[n=jt*64+t*16+(l&15)][m=ms*32+(l>>4)*8+e]
//  PhiKF[(jt*8 + ms)*4 + w][lane][e]  = phiK[n=jt*64+w*16+(l&15)][m=ms*32+(l>>4)*8+e]
//  PhiTF[(mq*8 + kt)*4 + t][lane][e]  = phiK[n=kt*32+(l>>4)*8+e][m=mq*64+t*16+(l&15)]
//  VTF  [(dvq*8 + kt)*4 + t][lane][e] = V   [n=kt*32+(l>>4)*8+e][dv=dvq*64+t*16+(l&15)]
//  STF  [(dvq*8 + ms)*4 + t2][lane][e]= S   [m=ms*32+(l>>4)*8+e][dv=dvq*64+t2*16+(l&15)]
// Every consumer fragment load = one contiguous 1KB wave-load.
// ---------------------------------------------------------------------------

__device__ __forceinline__ unsigned short f2bf(float x) {
    union { float f; unsigned int u; } v; v.f = x;
    unsigned int r = v.u + 0x7FFF + ((v.u >> 16) & 1);   // RNE
    return (unsigned short)(r >> 16);
}
__device__ __forceinline__ float bf2f(unsigned short u) {
    union { unsigned int u; float f; } v; v.u = ((unsigned int)u) << 16;
    return v.f;
}

// fp32 -> (hi: truncated bf16, lo: RNE bf16 of remainder); hi+lo ~ 2^-17 rel err
__device__ __forceinline__ void split4(const float4 x, unsigned short h[4], unsigned short l[4])
{
    const float xs[4] = {x.x, x.y, x.z, x.w};
#pragma unroll
    for (int j = 0; j < 4; ++j) {
        union { float f; unsigned u; } v; v.f = xs[j];
        const unsigned hm = v.u & 0xFFFF0000u;
        union { unsigned u; float f; } hv; hv.u = hm;
        h[j] = (unsigned short)(hm >> 16);
        l[j] = f2bf(xs[j] - hv.f);
    }
}

// ---------------------------------------------------------------------------
// K0: omega fp32 [256][256] -> hi/lo bf16 in MFMA FRAGMENT ORDER
// ---------------------------------------------------------------------------
__global__ __launch_bounds__(256) void omconv(
    const float* __restrict__ Om, unsigned short* __restrict__ OmH,
    unsigned short* __restrict__ OmL)
{
    const int i = blockIdx.x * 256 + threadIdx.x;   // 16384 threads, 4 els each
    const int row = i >> 6;          // 64 threads per 256-col row
    const int k0  = (i & 63) * 4;
    const float4 v = *(const float4*)(Om + (size_t)row * DD + k0);
    const int wv = row >> 6, ct = (row >> 4) & 3, colL = row & 15;
    const int kt = k0 >> 5, quad = (k0 >> 3) & 3, e0 = k0 & 7;
    const int lanep = quad * 16 + colL;
    const size_t off = ((size_t)((wv * 8 + kt) * 4 + ct) * 64 + lanep) * 8 + e0;
    unsigned short h[4], l[4];
    split4(v, h, l);
    *(uint2*)(OmH + off) = *(uint2*)h;
    *(uint2*)(OmL + off) = *(uint2*)l;
}

// ---------------------------------------------------------------------------
// K1 (fused Q+K+V): phi = exp(X@Om^T - rowmax)/16 via bf16 MFMA hi/lo.
// v7: three block ranges:
//   0..1023    K path -> PhiKF + PhiTF + Z
//   1024..2047 Q path -> PhiQF (fragment order, same encoding as PhiKF)
//   2048..4095 V path -> VTF (transpose_v fused in; aliases LDS)
// ---------------------------------------------------------------------------
__global__ __launch_bounds__(256, 4) void phi_fused(
    const float* __restrict__ Qp, const float* __restrict__ Kp,
    const float* __restrict__ Vp,
    const unsigned short* __restrict__ OmH, const unsigned short* __restrict__ OmL,
    unsigned short* __restrict__ PhiQF, unsigned short* __restrict__ PhiKF,
    unsigned short* __restrict__ PhiTF, unsigned short* __restrict__ VTF,
    float* __restrict__ Zp)
{
    const int tid = threadIdx.x;
    const int w = tid >> 6;
    const int lane = tid & 63;
    const int col = lane & 15, quad = lane >> 4;

    __shared__ __align__(16) short AhS[32][264];   // 16896 B  (pitch 264 shorts)
    __shared__ __align__(16) short AlS[32][264];   // 16896 B
    __shared__ float rowmax_s[32];
    float (*red)[68] = (float(*)[68])AhS;                     // epilogue alias (Ah dead)
    unsigned short (*P)[264] = (unsigned short(*)[264])AlS;   // epilogue alias (Al dead)
    unsigned int* P32 = (unsigned int*)AlS;

    if (blockIdx.x >= 2048) {
        // ---- V path: fp32 [64 rows][64 dv] tile -> VTF bf16 fragment order
        const int vid = blockIdx.x - 2048;
        const int ct = vid & 3;                        // dvq
        const long r0v = (long)(vid >> 2) * 64;
        const int b = (int)(r0v >> 12);
        const int n0 = (int)(r0v & (NN - 1));
        const int c = n0 >> 8;
        const int kt0 = (n0 & 255) >> 5;               // {0,2,4,6}
        const size_t bcv = ((size_t)(b * NC + c)) << 16;
        unsigned short (*T)[72] = (unsigned short(*)[72])AhS;   // 9216 B alias
        const int rr = tid >> 4, cs = tid & 15;
#pragma unroll
        for (int p = 0; p < 4; ++p) {
            const int r = p * 16 + rr;
            const float4 v = *(const float4*)(Vp + (r0v + r) * DV + ct * 64 + cs * 4);
            T[cs * 4 + 0][r] = f2bf(v.x); T[cs * 4 + 1][r] = f2bf(v.y);
            T[cs * 4 + 2][r] = f2bf(v.z); T[cs * 4 + 3][r] = f2bf(v.w);
        }
        __syncthreads();
        const int tq = w;
#pragma unroll
        for (int p = 0; p < 2; ++p) {
            const uint4 v = *(const uint4*)&T[tq * 16 + col][p * 32 + quad * 8];
            *(uint4*)(VTF + bcv + (((size_t)(ct * 8 + kt0 + p) * 4 + tq) * 64 + lane) * 8) = v;
        }
        return;
    }

    const bool kpath = blockIdx.x < 1024;
    const int id = kpath ? blockIdx.x : (blockIdx.x - 1024);
    const float* __restrict__ X = kpath ? Kp : Qp;
    const long r0 = (long)id * 32;

    // ---- stage: each wave loads its 8 rows, one full coalesced row per instr
    {
        float4 xv[8];
#pragma unroll
        for (int j = 0; j < 8; ++j) {
            const int row = w * 8 + j;
            xv[j] = *(const float4*)(X + (r0 + row) * DD + lane * 4);
        }
#pragma unroll
        for (int j = 0; j < 8; ++j) {
            const int row = w * 8 + j;
            unsigned short h[4], l[4];
            split4(xv[j], h, l);
            *(uint2*)&AhS[row][lane * 4] = *(uint2*)h;
            *(uint2*)&AlS[row][lane * 4] = *(uint2*)l;
        }
    }

    // ---- B-frag prefetch for kt=0 (packed layout: per-wave contiguous)
    const unsigned short* OmHw = OmH + (size_t)w * 8 * 4 * 512;
    const unsigned short* OmLw = OmL + (size_t)w * 8 * 4 * 512;
    f32x4 acc[2][4] = {};
    s16x8 bh0[4], bl0[4], bh1[4], bl1[4];
#pragma unroll
    for (int ct = 0; ct < 4; ++ct) {
        const size_t off = ((size_t)ct * 64 + lane) * 8;
        bh0[ct] = *(const s16x8*)(OmHw + off);
        bl0[ct] = *(const s16x8*)(OmLw + off);
    }
    __syncthreads();

    // ---- K loop: pure ds_read + MFMA, dbuf'd ideal Om loads
#pragma unroll
    for (int kt = 0; kt < 8; ++kt) {
        if (kt < 7) {
#pragma unroll
            for (int ct = 0; ct < 4; ++ct) {
                const size_t off = ((size_t)((kt + 1) * 4 + ct) * 64 + lane) * 8;
                bh1[ct] = *(const s16x8*)(OmHw + off);
                bl1[ct] = *(const s16x8*)(OmLw + off);
            }
        }
#pragma unroll
        for (int t = 0; t < 2; ++t) {
            const s16x8 ah = *(const s16x8*)&AhS[t * 16 + col][kt * 32 + quad * 8];
            const s16x8 al = *(const s16x8*)&AlS[t * 16 + col][kt * 32 + quad * 8];
#pragma unroll
            for (int ct = 0; ct < 4; ++ct) {
                acc[t][ct] = MFMA16(ah, bh0[ct], acc[t][ct]);
                acc[t][ct] = MFMA16(ah, bl0[ct], acc[t][ct]);
                acc[t][ct] = MFMA16(al, bh0[ct], acc[t][ct]);
            }
        }
#pragma unroll
        for (int ct = 0; ct < 4; ++ct) { bh0[ct] = bh1[ct]; bl0[ct] = bl1[ct]; }
    }

    // ---- row max over 256 cols (red aliases AhS: barrier first)
    __syncthreads();
#pragma unroll
    for (int t = 0; t < 2; ++t)
#pragma unroll
        for (int r = 0; r < 4; ++r) {
            float m = acc[t][0][r];
#pragma unroll
            for (int ct = 1; ct < 4; ++ct) m = fmaxf(m, acc[t][ct][r]);
            red[t * 16 + quad * 4 + r][w * 16 + col] = m;
        }
    __syncthreads();
    {   // parallel reduce: 8 lanes per row + shfl tree
        const int row = tid >> 3, seg = tid & 7;
        float m = red[row][seg * 8];
#pragma unroll
        for (int j = 1; j < 8; ++j) m = fmaxf(m, red[row][seg * 8 + j]);
        m = fmaxf(m, __shfl_xor(m, 1));
        m = fmaxf(m, __shfl_xor(m, 2));
        m = fmaxf(m, __shfl_xor(m, 4));
        if (seg == 0) rowmax_s[row] = m;
    }
    __syncthreads();

    // ---- exp epilogue -> P[n][m] bf16 (P aliases AlS: dead)
#pragma unroll
    for (int t = 0; t < 2; ++t)
#pragma unroll
        for (int r = 0; r < 4; ++r) {
            const int n = t * 16 + quad * 4 + r;
            const float rm = rowmax_s[n];
#pragma unroll
            for (int ct = 0; ct < 4; ++ct) {
                const float val = __expf(acc[t][ct][r] - rm) * 0.0625f;
                const unsigned u = (unsigned)f2bf(val);
                const unsigned up = (unsigned)__shfl_xor((int)u, 1);
                if ((col & 1) == 0)
                    P32[n * 132 + w * 32 + ct * 8 + (col >> 1)] = u | (up << 16);
            }
        }
    __syncthreads();

    {
        const int b = id >> 7;              // 128 blocks per batch
        const int ib = id & 127;
        const int c = ib >> 3;              // 8 blocks per 256-row chunk
        const size_t bc = ((size_t)(b * NC + c)) << 16;
        const int jt = (ib >> 1) & 3;       // 64-row k-group within chunk
        const int half = ib & 1;            // which 32-row half of the jt group
        unsigned short* __restrict__ PF = kpath ? PhiKF : PhiQF;
        // frag store: rows = n (jt, t=half*2+wl), contraction = m. 16B LDS reads.
#pragma unroll
        for (int p = 0; p < 4; ++p) {
            const int msw = p * 4 + w;
            const int ms = msw >> 1, wl = msw & 1;
            const uint4 v = *(const uint4*)&P[wl * 16 + col][ms * 32 + quad * 8];
            *(uint4*)(PF + bc + (((size_t)(jt * 8 + ms) * 4 + half * 2 + wl) * 64 + lane) * 8) = v;
        }
        if (kpath) {
            const int ktp = ib & 7;             // 32-row k-subtile within chunk
            // PhiTF: frag rows = m (mq,t), contraction = n. column gather.
#pragma unroll
            for (int p = 0; p < 4; ++p) {
                const int mq = p, t = w;
                unsigned short u[8];
#pragma unroll
                for (int e = 0; e < 8; ++e)
                    u[e] = P[quad * 8 + e][mq * 64 + t * 16 + col];
                *(uint4*)(PhiTF + bc + (((size_t)(mq * 8 + ktp) * 4 + t) * 64 + lane) * 8) = *(uint4*)u;
            }
            float z = 0.f;
#pragma unroll
            for (int n = 0; n < 32; ++n) z += bf2f(P[n][tid]);
            atomicAdd(&Zp[((b * NC + c) << 8) + tid], z);
        }
    }
}

// ---------------------------------------------------------------------------
// K2: per-chunk S_c[m][dv] = sum_n phi_k[n][m]*V[n][dv]  (bf16 MFMA)
// All operand loads are ideal 1KB fragment loads; C-write coalesced uint2.
// ---------------------------------------------------------------------------
__global__ __launch_bounds__(256, 3) void state_mfma(
    const unsigned short* __restrict__ VTF, const unsigned short* __restrict__ PhiTF,
    unsigned short* __restrict__ STF)
{
    const int tid = threadIdx.x;
    const int w = tid >> 6;
    const int lane = tid & 63;
    const int col = lane & 15, quad = lane >> 4;
    const int q  = blockIdx.x >> 7;
    const int bci = blockIdx.x & 127;
    const int c  = bci & 15;
    const int b  = bci >> 4;
    const int dvq = (q & 1) * 2 + (w & 1);
    const int mq  = (q >> 1) * 2 + (w >> 1);
    const size_t bc = ((size_t)(b * NC + c)) << 16;
    const unsigned short* Af = VTF   + bc + (size_t)dvq * 16384;
    const unsigned short* Bf = PhiTF + bc + (size_t)mq  * 16384;

    f32x4 acc[4][4] = {};   // [i = m-sub][j = dv-sub]
    s16x8 a0[4], b0[4], a1[4], b1[4];
#pragma unroll
    for (int t = 0; t < 4; ++t) {
        a0[t] = *(const s16x8*)(Af + ((size_t)t * 64 + lane) * 8);
        b0[t] = *(const s16x8*)(Bf + ((size_t)t * 64 + lane) * 8);
    }
#pragma unroll
    for (int kt = 0; kt < 8; ++kt) {
        if (kt < 7) {
#pragma unroll
            for (int t = 0; t < 4; ++t) {
                a1[t] = *(const s16x8*)(Af + ((size_t)((kt + 1) * 4 + t) * 64 + lane) * 8);
                b1[t] = *(const s16x8*)(Bf + ((size_t)((kt + 1) * 4 + t) * 64 + lane) * 8);
            }
        }
#pragma unroll
        for (int i = 0; i < 4; ++i)
#pragma unroll
            for (int j = 0; j < 4; ++j) acc[i][j] = MFMA16(b0[i], a0[j], acc[i][j]);
#pragma unroll
        for (int t = 0; t < 4; ++t) { a0[t] = a1[t]; b0[t] = b1[t]; }
    }
    // C-write: STF element (dvq, ms=mq*2+(i>>1), t2=j, lane', e) — coalesced 8B stores
#pragma unroll
    for (int i = 0; i < 4; ++i)
#pragma unroll
        for (int j = 0; j < 4; ++j) {
            unsigned short s[4];
#pragma unroll
            for (int r = 0; r < 4; ++r) s[r] = f2bf(acc[i][j][r]);
            const int lanep = ((i & 1) * 2 + (quad >> 1)) * 16 + col;
            const size_t off = (((size_t)(dvq * 8 + mq * 2 + (i >> 1)) * 4 + j) * 64 + lanep) * 8 + (quad & 1) * 4;
            *(uint2*)(STF + bc + off) = *(uint2*)s;
        }
}

// ---------------------------------------------------------------------------
// K3: in-place exclusive prefix over chunks: STF (bf16), Z (fp32)
// ---------------------------------------------------------------------------
__global__ __launch_bounds__(256) void prefix2(
    unsigned short* __restrict__ ST, float* __restrict__ Z)
{
    const long idx = (long)blockIdx.x * 256 + threadIdx.x;
    const int b = (int)(idx >> 16);
    const int r = (int)(idx & 65535);
    float run = 0.f;
#pragma unroll
    for (int c = 0; c < NC; ++c) {
        const size_t off = (((size_t)(b * NC + c)) << 16) + r;
        const float v = bf2f(ST[off]);
        ST[off] = f2bf(run);
        run += v;
    }
    if (idx < BN * MM) {
        const int b2 = (int)(idx >> 8);
        const int m = (int)(idx & 255);
        float rz = 0.f;
#pragma unroll
        for (int c = 0; c < NC; ++c) {
            const size_t off = (size_t)(b2 * NC + c) * MM + m;
            const float v = Z[off];
            Z[off] = rz;
            rz += v;
        }
    }
}

// ---------------------------------------------------------------------------
// K4: out = (intra causal A@V + phi_q@S_pre) / (rowsum(A) + phi_q.z_pre)
// v7: no Q LDS staging — all A/B operands are ideal 1KB frag loads from L2.
// Denominator folded into the S-loop (per-wave ms slice of phi_q·z).
// LDS 61.7 KB -> 15.7 KB.
// ---------------------------------------------------------------------------
__global__ __launch_bounds__(256) void out_mfma(
    const unsigned short* __restrict__ PhiQF, const unsigned short* __restrict__ PhiKF,
    const unsigned short* __restrict__ VTF, const unsigned short* __restrict__ STF,
    const float* __restrict__ Z, float* __restrict__ Out)
{
    const int tid = threadIdx.x;
    const int w = tid >> 6;
    const int lane = tid & 63;
    const int col = lane & 15, quad = lane >> 4;
    const int it = 3 - (blockIdx.x >> 7);
    const int low = blockIdx.x & 127;
    const int c  = low & 15;
    const int b  = low >> 4;
    const size_t chunk_row = (size_t)b * NN + (size_t)c * CHUNK;
    const size_t bc = ((size_t)(b * NC + c)) << 16;
    const unsigned short* Qf = PhiQF + bc + (size_t)it * 16384;   // this block's q-row frag group
    const unsigned short* Vf = VTF + bc + (size_t)w * 16384;
    const unsigned short* Sf = STF + bc + (size_t)w * 16384;

    __shared__ unsigned short A_s[64][72];   // 9216 B
    __shared__ float red[64][20];            // 5120 B: [0..3]=A-rowsum by w, [4..19]=q·z by (w,quad)
    __shared__ float z_s[256];
    __shared__ float den_s[64];

    z_s[tid] = Z[(bc >> 8) + tid];

    f32x4 oacc[4][4] = {};
    float rsum[4][4] = {};

    for (int jt = 0; jt <= it; ++jt) {
        f32x4 accA[4] = {};
        // QK^T: per ms: 1 bk frag + 4 aq frags (all ideal 1KB, L2-hot)
#pragma unroll
        for (int ms = 0; ms < 8; ++ms) {
            const s16x8 bk = *(const s16x8*)(PhiKF + bc + (((size_t)(jt * 8 + ms) * 4 + w) * 64 + lane) * 8);
            s16x8 aq[4];
#pragma unroll
            for (int t = 0; t < 4; ++t)
                aq[t] = *(const s16x8*)(Qf + (((size_t)ms * 4 + t) * 64 + lane) * 8);
#pragma unroll
            for (int t = 0; t < 4; ++t)
                accA[t] = MFMA16(aq[t], bk, accA[t]);
        }
        __syncthreads();   // protects A_s from previous iter's PV reads
#pragma unroll
        for (int t = 0; t < 4; ++t)
#pragma unroll
            for (int r = 0; r < 4; ++r) {
                const int i_loc = t * 16 + quad * 4 + r;
                const int j_loc = w * 16 + col;
                float v = (jt * 64 + j_loc <= it * 64 + i_loc) ? accA[t][r] : 0.f;
                rsum[t][r] += v;
                A_s[i_loc][j_loc] = f2bf(v);
            }
        __syncthreads();
        // PV: A_s @ V-frags
#pragma unroll
        for (int ks2 = 0; ks2 < 2; ++ks2) {
            s16x8 bv[4];
#pragma unroll
            for (int t2 = 0; t2 < 4; ++t2)
                bv[t2] = *(const s16x8*)(Vf + (((size_t)(jt * 2 + ks2) * 4 + t2) * 64 + lane) * 8);
            s16x8 av[4];
#pragma unroll
            for (int t = 0; t < 4; ++t)
                av[t] = *(const s16x8*)&A_s[t * 16 + col][ks2 * 32 + quad * 8];
#pragma unroll
            for (int t2 = 0; t2 < 4; ++t2)
#pragma unroll
                for (int t = 0; t < 4; ++t)
                    oacc[t][t2] = MFMA16(av[t], bv[t2], oacc[t][t2]);
        }
    }

    // A-rowsum: reduce across the wave's 16 cols, deposit per-w partial
#pragma unroll
    for (int t = 0; t < 4; ++t)
#pragma unroll
        for (int r = 0; r < 4; ++r) {
            float v = rsum[t][r];
            v += __shfl_xor(v, 1);
            v += __shfl_xor(v, 2);
            v += __shfl_xor(v, 4);
            v += __shfl_xor(v, 8);
            if (col == 0) red[t * 16 + quad * 4 + r][w] = v;
        }

    // S-loop: oacc += phi_q @ S_pre; den partials for ms = {2w, 2w+1}
    float dpart[4] = {0.f, 0.f, 0.f, 0.f};
#pragma unroll
    for (int ms = 0; ms < 8; ++ms) {
        s16x8 bs[4], aq[4];
#pragma unroll
        for (int t2 = 0; t2 < 4; ++t2)
            bs[t2] = *(const s16x8*)(Sf + (((size_t)ms * 4 + t2) * 64 + lane) * 8);
#pragma unroll
        for (int t = 0; t < 4; ++t)
            aq[t] = *(const s16x8*)(Qf + (((size_t)ms * 4 + t) * 64 + lane) * 8);
#pragma unroll
        for (int t2 = 0; t2 < 4; ++t2)
#pragma unroll
            for (int t = 0; t < 4; ++t)
                oacc[t][t2] = MFMA16(aq[t], bs[t2], oacc[t][t2]);
        if ((ms >> 1) == w) {
#pragma unroll
            for (int t = 0; t < 4; ++t)
#pragma unroll
                for (int e = 0; e < 8; ++e)
                    dpart[t] = fmaf(bf2f((unsigned short)aq[t][e]),
                                    z_s[ms * 32 + quad * 8 + e], dpart[t]);
        }
    }
#pragma unroll
    for (int t = 0; t < 4; ++t)
        red[t * 16 + col][4 + w * 4 + quad] = dpart[t];
    __syncthreads();
    if (tid < 64) {
        float s = 0.f;
#pragma unroll
        for (int j = 0; j < 20; ++j) s += red[tid][j];
        den_s[tid] = fmaxf(s, 1e-6f);
    }
    __syncthreads();
#pragma unroll
    for (int t = 0; t < 4; ++t)
#pragma unroll
        for (int r = 0; r < 4; ++r) {
            const int i_loc = t * 16 + quad * 4 + r;
            const float invd = 1.0f / den_s[i_loc];
#pragma unroll
            for (int t2 = 0; t2 < 4; ++t2)
                Out[(chunk_row + it * 64 + i_loc) * DV + w * 64 + t2 * 16 + col] = oacc[t][t2][r] * invd;
        }
}

extern "C" void kernel_launch(void* const* d_in, const int* in_sizes, int n_in,
                              void* d_out, int out_size, void* d_ws, size_t ws_size,
                              hipStream_t stream)
{
    const float* Q  = (const float*)d_in[0];
    const float* K  = (const float*)d_in[1];
    const float* V  = (const float*)d_in[2];
    const float* Om = (const float*)d_in[3];
    float* out = (float*)d_out;

    const size_t NM = (size_t)BN * NN * MM;
    unsigned short* PhiQF = (unsigned short*)d_ws;
    unsigned short* PhiKF = PhiQF + NM;
    unsigned short* PhiTF = PhiKF + NM;
    unsigned short* VTF   = PhiTF + NM;
    unsigned short* STF   = VTF + NM;
    unsigned short* OmH   = STF + (size_t)BN * NC * DV * MM;
    unsigned short* OmL   = OmH + (size_t)MM * DD;
    float* Z = (float*)(OmL + (size_t)MM * DD);

    hipMemsetAsync(Z, 0, (size_t)BN * NC * MM * sizeof(float), stream);
    omconv<<<dim3(64), dim3(256), 0, stream>>>(Om, OmH, OmL);
    phi_fused<<<dim3(4096), dim3(256), 0, stream>>>(Q, K, V, OmH, OmL, PhiQF, PhiKF, PhiTF, VTF, Z);
    state_mfma<<<dim3(BN * NC * 4), dim3(256), 0, stream>>>(VTF, PhiTF, STF);
    prefix2<<<dim3((BN * DV * MM) / 256), dim3(256), 0, stream>>>(STF, Z);
    out_mfma<<<dim3(BN * NC * 4), dim3(256), 0, stream>>>(PhiQF, PhiKF, VTF, STF, Z, out);
}